// Round 6
// baseline (659.323 us; speedup 1.0000x reference)
//
#include <hip/hip_runtime.h>
#include <math.h>

#define NN 10000
#define GG 12
#define CC 64
#define AA 3
#define EE 50000
#define LN_EPS 1e-5f
#define MAXDEG 64   // max in-degree cap; Poisson(E/N=5) max ~17, 64 is far beyond

__device__ __forceinline__ int rfl(int v) { return __builtin_amdgcn_readfirstlane(v); }
__device__ __forceinline__ float bl(float v, int i) {
    return __uint_as_float(__builtin_amdgcn_readlane(__float_as_uint(v), i));
}

// ---------------- kernel 1: zero per-node counters ----------------
__global__ __launch_bounds__(256) void zero_cnt(int* __restrict__ cnt) {
    int i = blockIdx.x * 256 + threadIdx.x;
    if (i < NN) cnt[i] = 0;
}

// ---------------- kernel 2: bucket edges by destination; pack e | src<<17 ----------------
__global__ __launch_bounds__(256) void bucket_fill(const int* __restrict__ ei,
                                                   int* __restrict__ cnt,
                                                   int* __restrict__ elist) {
    int e = blockIdx.x * 256 + threadIdx.x;
    if (e < EE) {
        int src = ei[e];
        int dst = ei[EE + e];
        int pos = atomicAdd(&cnt[dst], 1);
        if (pos < MAXDEG) elist[dst * MAXDEG + pos] = e | (src << 17);
    }
}

// ---------------- kernel 3: conv gather — attr via per-wave LDS slot ----------------
// block = node, 4 waves; wave wv owns g = 3wv, 3wv+1, 3wv+2; lane = channel.
// Per edge: attr block (432 f) loaded as 2 coalesced dwordx4/lane (windows [0..255]
// and [176..431]), staged in a PRIVATE double-buffered LDS slot (no barriers), read
// back as 27 broadcast ds_read_b128 with compile-time component extraction.
// Node's packed edge list lives in 1 VGPR/lane; per-edge handle via v_readlane.
__global__ __launch_bounds__(256, 4) void conv_gather(
    const float* __restrict__ x, const float* __restrict__ attr,
    const float* __restrict__ Wk,
    const int* __restrict__ cnt, const int* __restrict__ elist,
    float* __restrict__ agg) {
    __shared__ float lds[4 * 2 * 432];           // 13.8 KB: 4 waves x 2 slots x 432 f

    const int n    = blockIdx.x;
    const int lane = threadIdx.x & 63;
    const int wv   = rfl((int)threadIdx.x >> 6); // 0..3 -> g-triple
    float* const sbase = &lds[wv * 864];

    const float wk0 = Wk[lane];
    const float wk1 = Wk[CC + lane];
    const float wk2 = Wk[2 * CC + lane];

    const int deg = min(cnt[n], MAXDEG);
    const int myE = elist[n * MAXDEG + lane];    // whole edge list in registers

    float acc[3] = {0.f, 0.f, 0.f};
    float xrc[GG];

    // ---- prologue: stage edge 0 ----
    if (deg > 0) {
        const int p = __builtin_amdgcn_readlane(myE, 0);
        const float* ap = attr + (size_t)(p & 0x1FFFF) * (GG * GG * AA);
        const float4 a0 = *(const float4*)(ap + 4 * lane);
        const float4 a1 = *(const float4*)(ap + 176 + 4 * lane);
        const float* xp = x + (p >> 17) * (GG * CC) + lane;
#pragma unroll
        for (int h = 0; h < GG; ++h) xrc[h] = xp[h * CC];
        *(float4*)(sbase + 4 * lane) = a0;
        *(float4*)(sbase + 176 + 4 * lane) = a1;
    }

    for (int i = 0; i < deg; ++i) {
        // ---- prefetch edge i+1 (global -> VGPR) ----
        float4 An0, An1;
        float xrn[GG];
        const bool pf = (i + 1) < deg;
        if (pf) {
            const int p = __builtin_amdgcn_readlane(myE, i + 1);
            const float* ap = attr + (size_t)(p & 0x1FFFF) * (GG * GG * AA);
            An0 = *(const float4*)(ap + 4 * lane);
            An1 = *(const float4*)(ap + 176 + 4 * lane);
            const float* xp = x + (p >> 17) * (GG * CC) + lane;
#pragma unroll
            for (int h = 0; h < GG; ++h) xrn[h] = xp[h * CC];
        }

        // ---- compute edge i from LDS slot (broadcast reads, no conflicts) ----
        const float* sp = sbase + (i & 1) * 432;
#pragma unroll
        for (int j = 0; j < 3; ++j) {
            const float* gp = sp + wv * 108 + j * 36;   // g = 3*wv + j
            float qq[36];
#pragma unroll
            for (int r = 0; r < 9; ++r) {
                const float4 v = *(const float4*)(gp + 4 * r);
                qq[4 * r + 0] = v.x; qq[4 * r + 1] = v.y;
                qq[4 * r + 2] = v.z; qq[4 * r + 3] = v.w;
            }
            float t0 = 0.f, t1 = 0.f, t2 = 0.f;
#pragma unroll
            for (int h = 0; h < GG; ++h) {
                t0 = fmaf(qq[h * 3 + 0], xrc[h], t0);
                t1 = fmaf(qq[h * 3 + 1], xrc[h], t1);
                t2 = fmaf(qq[h * 3 + 2], xrc[h], t2);
            }
            acc[j] = fmaf(t0, wk0, fmaf(t1, wk1, fmaf(t2, wk2, acc[j])));
        }

        // ---- stage edge i+1 (VGPR -> LDS other slot) ----
        if (pf) {
            float* dp = sbase + ((i + 1) & 1) * 432;
            *(float4*)(dp + 4 * lane) = An0;
            *(float4*)(dp + 176 + 4 * lane) = An1;
#pragma unroll
            for (int h = 0; h < GG; ++h) xrc[h] = xrn[h];
        }
    }

#pragma unroll
    for (int j = 0; j < 3; ++j)
        agg[(n * GG + wv * 3 + j) * CC + lane] = acc[j];
}

// ---------------- kernel 4: LN + MLP(GELU) + layer_scale + residual ----------------
__global__ __launch_bounds__(256, 2) void ln_mlp(
    const float* __restrict__ x, const float* __restrict__ cb,
    const float* __restrict__ lnw, const float* __restrict__ lnb,
    const float* __restrict__ W1, const float* __restrict__ b1,
    const float* __restrict__ W2, const float* __restrict__ b2,
    const float* __restrict__ ls, float* __restrict__ out) {
    const int lane = threadIdx.x & 63;
    const int wv   = threadIdx.x >> 6;

    float w1r[CC], w2r[CC];
#pragma unroll
    for (int i = 0; i < CC; ++i) {
        w1r[i] = W1[i * CC + lane];
        w2r[i] = W2[i * CC + lane];
    }
    const float cbv = cb[lane];
    const float lw  = lnw[lane], lb = lnb[lane];
    const float bb1 = b1[lane],  bb2 = b2[lane];
    const float lsc = ls[lane];

    const int nf = NN * GG;
    const int nw = gridDim.x * 4;
    for (int f = blockIdx.x * 4 + wv; f < nf; f += nw) {
        const float v = out[f * CC + lane] + cbv;   // agg written here by conv_gather
        float s = v, s2 = v * v;
#pragma unroll
        for (int off = 32; off; off >>= 1) {
            s  += __shfl_xor(s,  off);
            s2 += __shfl_xor(s2, off);
        }
        const float mu  = s * (1.f / 64.f);
        const float var = s2 * (1.f / 64.f) - mu * mu;
        const float hh  = (v - mu) * rsqrtf(var + LN_EPS) * lw + lb;

        float a0 = 0.f, a1 = 0.f, a2 = 0.f, a3 = 0.f;
#pragma unroll
        for (int i = 0; i < CC; i += 4) {
            a0 = fmaf(bl(hh, i),     w1r[i],     a0);
            a1 = fmaf(bl(hh, i + 1), w1r[i + 1], a1);
            a2 = fmaf(bl(hh, i + 2), w1r[i + 2], a2);
            a3 = fmaf(bl(hh, i + 3), w1r[i + 3], a3);
        }
        const float z  = ((a0 + a1) + (a2 + a3)) + bb1;
        const float gl = 0.5f * z * (1.f + erff(z * 0.70710678118654752f));

        float c0 = 0.f, c1 = 0.f, c2 = 0.f, c3 = 0.f;
#pragma unroll
        for (int i = 0; i < CC; i += 4) {
            c0 = fmaf(bl(gl, i),     w2r[i],     c0);
            c1 = fmaf(bl(gl, i + 1), w2r[i + 1], c1);
            c2 = fmaf(bl(gl, i + 2), w2r[i + 2], c2);
            c3 = fmaf(bl(gl, i + 3), w2r[i + 3], c3);
        }
        const float z2 = ((c0 + c1) + (c2 + c3)) + bb2;

        out[f * CC + lane] = fmaf(lsc, z2, x[f * CC + lane]);
    }
}

extern "C" void kernel_launch(void* const* d_in, const int* in_sizes, int n_in,
                              void* d_out, int out_size, void* d_ws, size_t ws_size,
                              hipStream_t stream) {
    const float* x    = (const float*)d_in[0];
    const float* attr = (const float*)d_in[1];
    const float* Wk   = (const float*)d_in[2];
    const float* cb   = (const float*)d_in[3];
    const float* lnw  = (const float*)d_in[4];
    const float* lnb  = (const float*)d_in[5];
    const float* W1   = (const float*)d_in[6];
    const float* b1   = (const float*)d_in[7];
    const float* W2   = (const float*)d_in[8];
    const float* b2   = (const float*)d_in[9];
    const float* ls   = (const float*)d_in[10];
    const int*   ei   = (const int*)d_in[11];
    float* out = (float*)d_out;

    int* cnt   = (int*)d_ws;            // NN ints
    int* elist = cnt + NN;              // NN*MAXDEG ints (2.56 MB)

    zero_cnt<<<(NN + 255) / 256, 256, 0, stream>>>(cnt);
    bucket_fill<<<(EE + 255) / 256, 256, 0, stream>>>(ei, cnt, elist);
    conv_gather<<<NN, 256, 0, stream>>>(x, attr, Wk, cnt, elist, out);
    ln_mlp<<<512, 256, 0, stream>>>(x, cb, lnw, lnb, W1, b1, W2, b2, ls, out);
}

// Round 7
// 181.026 us; speedup vs baseline: 3.6421x; 3.6421x over previous
//
#include <hip/hip_runtime.h>
#include <math.h>

#define NN 10000
#define GG 12
#define CC 64
#define AA 3
#define EE 50000
#define LN_EPS 1e-5f
#define MAXDEG 64   // max in-degree cap; Poisson(E/N=5) max ~17, 64 is far beyond

__device__ __forceinline__ int rfl(int v) { return __builtin_amdgcn_readfirstlane(v); }
__device__ __forceinline__ float bl(float v, int i) {
    return __uint_as_float(__builtin_amdgcn_readlane(__float_as_uint(v), i));
}
// readlane where the index is a compile-time constant after unroll
#define RL(reg, idx) __uint_as_float(__builtin_amdgcn_readlane(__float_as_uint(reg), (idx)))

// ---------------- kernel 1: zero per-node counters ----------------
__global__ __launch_bounds__(256) void zero_cnt(int* __restrict__ cnt) {
    int i = blockIdx.x * 256 + threadIdx.x;
    if (i < NN) cnt[i] = 0;
}

// ---------------- kernel 2: bucket edges by destination; pack e | src<<17 ----------------
__global__ __launch_bounds__(256) void bucket_fill(const int* __restrict__ ei,
                                                   int* __restrict__ cnt,
                                                   int* __restrict__ elist) {
    int e = blockIdx.x * 256 + threadIdx.x;
    if (e < EE) {
        int src = ei[e];
        int dst = ei[EE + e];
        int pos = atomicAdd(&cnt[dst], 1);
        if (pos < MAXDEG) elist[dst * MAXDEG + pos] = e | (src << 17);
    }
}

// ---------------- kernel 3: conv gather — compile-time readlane broadcast ----------------
// block = node, 8 waves: wave = (parity ew, g-triple gw); wave gw owns g = 3gw..3gw+2.
// The wave's 108 contiguous attr floats live in TWO regs/lane:
//   R0 = window[lane]  (floats 0..63), R1 = window[44+lane] (floats 64..107 at lanes 20..63)
// -> every attr scalar is one v_readlane with a compile-time lane index.
// Node's packed edge list in 1 VGPR/lane (myE); depth-2 software pipeline.
__global__ __launch_bounds__(512) void conv_gather(
    const float* __restrict__ x, const float* __restrict__ attr,
    const float* __restrict__ Wk,
    const int* __restrict__ cnt, const int* __restrict__ elist,
    float* __restrict__ agg) {
    __shared__ float red[4][3][CC];            // 3 KB: parity-1 partials

    const int n    = blockIdx.x;
    const int t    = threadIdx.x;
    const int lane = t & 63;
    const int w    = rfl(t >> 6);
    const int gw   = w & 3;                    // g = 3gw, 3gw+1, 3gw+2
    const int ew   = w >> 2;                   // edge parity 0/1

    const float wk0 = Wk[lane];
    const float wk1 = Wk[CC + lane];
    const float wk2 = Wk[2 * CC + lane];

    const int deg = min(cnt[n], MAXDEG);
    const int myE = elist[n * MAXDEG + lane];  // whole edge list in registers

    float acc[3] = {0.f, 0.f, 0.f};
    float R0c = 0.f, R1c = 0.f;
    float xrc[GG];

    int i = ew;
    if (i < deg) {
        const int p = __builtin_amdgcn_readlane(myE, i);
        const float* ap = attr + (size_t)(p & 0x1FFFF) * (GG * GG * AA) + gw * 108;
        R0c = ap[lane];
        R1c = ap[44 + lane];
        const float* xp = x + (p >> 17) * (GG * CC) + lane;
#pragma unroll
        for (int h = 0; h < GG; ++h) xrc[h] = xp[h * CC];
    }

    for (; i < deg; i += 2) {
        // ---- prefetch edge i+2 (same parity) while computing edge i ----
        float R0n = 0.f, R1n = 0.f;
        float xrn[GG];
        const bool pf = (i + 2) < deg;
        if (pf) {
            const int p = __builtin_amdgcn_readlane(myE, i + 2);
            const float* ap = attr + (size_t)(p & 0x1FFFF) * (GG * GG * AA) + gw * 108;
            R0n = ap[lane];
            R1n = ap[44 + lane];
            const float* xp = x + (p >> 17) * (GG * CC) + lane;
#pragma unroll
            for (int h = 0; h < GG; ++h) xrn[h] = xp[h * CC];
        } else {
#pragma unroll
            for (int h = 0; h < GG; ++h) xrn[h] = 0.f;
        }

        // ---- compute edge i: attr scalars via compile-time readlane ----
#pragma unroll
        for (int j = 0; j < 3; ++j) {
            float t0 = 0.f, t1 = 0.f, t2 = 0.f;
#pragma unroll
            for (int h = 0; h < GG; ++h) {
                const int k = j * 36 + h * 3;          // 0..105, compile-time
                const float xv = xrc[h];
                const float v0 = (k     < 64) ? RL(R0c, k)     : RL(R1c, k - 44);
                const float v1 = (k + 1 < 64) ? RL(R0c, k + 1) : RL(R1c, k - 43);
                const float v2 = (k + 2 < 64) ? RL(R0c, k + 2) : RL(R1c, k - 42);
                t0 = fmaf(v0, xv, t0);
                t1 = fmaf(v1, xv, t1);
                t2 = fmaf(v2, xv, t2);
            }
            acc[j] = fmaf(t0, wk0, fmaf(t1, wk1, fmaf(t2, wk2, acc[j])));
        }

        R0c = R0n; R1c = R1n;
#pragma unroll
        for (int h = 0; h < GG; ++h) xrc[h] = xrn[h];
    }

    // ---- cross-parity reduction + store ----
    if (ew == 1) {
#pragma unroll
        for (int j = 0; j < 3; ++j) red[gw][j][lane] = acc[j];
    }
    __syncthreads();
    if (ew == 0) {
#pragma unroll
        for (int j = 0; j < 3; ++j)
            agg[(n * GG + gw * 3 + j) * CC + lane] = acc[j] + red[gw][j][lane];
    }
}

// ---------------- kernel 4: LN + MLP(GELU) + layer_scale + residual ----------------
__global__ __launch_bounds__(256, 2) void ln_mlp(
    const float* __restrict__ x, const float* __restrict__ cb,
    const float* __restrict__ lnw, const float* __restrict__ lnb,
    const float* __restrict__ W1, const float* __restrict__ b1,
    const float* __restrict__ W2, const float* __restrict__ b2,
    const float* __restrict__ ls, float* __restrict__ out) {
    const int lane = threadIdx.x & 63;
    const int wv   = threadIdx.x >> 6;

    float w1r[CC], w2r[CC];
#pragma unroll
    for (int i = 0; i < CC; ++i) {
        w1r[i] = W1[i * CC + lane];
        w2r[i] = W2[i * CC + lane];
    }
    const float cbv = cb[lane];
    const float lw  = lnw[lane], lb = lnb[lane];
    const float bb1 = b1[lane],  bb2 = b2[lane];
    const float lsc = ls[lane];

    const int nf = NN * GG;
    const int nw = gridDim.x * 4;
    for (int f = blockIdx.x * 4 + wv; f < nf; f += nw) {
        const float v = out[f * CC + lane] + cbv;   // agg written here by conv_gather
        float s = v, s2 = v * v;
#pragma unroll
        for (int off = 32; off; off >>= 1) {
            s  += __shfl_xor(s,  off);
            s2 += __shfl_xor(s2, off);
        }
        const float mu  = s * (1.f / 64.f);
        const float var = s2 * (1.f / 64.f) - mu * mu;
        const float hh  = (v - mu) * rsqrtf(var + LN_EPS) * lw + lb;

        float a0 = 0.f, a1 = 0.f, a2 = 0.f, a3 = 0.f;
#pragma unroll
        for (int i = 0; i < CC; i += 4) {
            a0 = fmaf(bl(hh, i),     w1r[i],     a0);
            a1 = fmaf(bl(hh, i + 1), w1r[i + 1], a1);
            a2 = fmaf(bl(hh, i + 2), w1r[i + 2], a2);
            a3 = fmaf(bl(hh, i + 3), w1r[i + 3], a3);
        }
        const float z  = ((a0 + a1) + (a2 + a3)) + bb1;
        const float gl = 0.5f * z * (1.f + erff(z * 0.70710678118654752f));

        float c0 = 0.f, c1 = 0.f, c2 = 0.f, c3 = 0.f;
#pragma unroll
        for (int i = 0; i < CC; i += 4) {
            c0 = fmaf(bl(gl, i),     w2r[i],     c0);
            c1 = fmaf(bl(gl, i + 1), w2r[i + 1], c1);
            c2 = fmaf(bl(gl, i + 2), w2r[i + 2], c2);
            c3 = fmaf(bl(gl, i + 3), w2r[i + 3], c3);
        }
        const float z2 = ((c0 + c1) + (c2 + c3)) + bb2;

        out[f * CC + lane] = fmaf(lsc, z2, x[f * CC + lane]);
    }
}

extern "C" void kernel_launch(void* const* d_in, const int* in_sizes, int n_in,
                              void* d_out, int out_size, void* d_ws, size_t ws_size,
                              hipStream_t stream) {
    const float* x    = (const float*)d_in[0];
    const float* attr = (const float*)d_in[1];
    const float* Wk   = (const float*)d_in[2];
    const float* cb   = (const float*)d_in[3];
    const float* lnw  = (const float*)d_in[4];
    const float* lnb  = (const float*)d_in[5];
    const float* W1   = (const float*)d_in[6];
    const float* b1   = (const float*)d_in[7];
    const float* W2   = (const float*)d_in[8];
    const float* b2   = (const float*)d_in[9];
    const float* ls   = (const float*)d_in[10];
    const int*   ei   = (const int*)d_in[11];
    float* out = (float*)d_out;

    int* cnt   = (int*)d_ws;            // NN ints
    int* elist = cnt + NN;              // NN*MAXDEG ints (2.56 MB)

    zero_cnt<<<(NN + 255) / 256, 256, 0, stream>>>(cnt);
    bucket_fill<<<(EE + 255) / 256, 256, 0, stream>>>(ei, cnt, elist);
    conv_gather<<<NN, 512, 0, stream>>>(x, attr, Wk, cnt, elist, out);
    ln_mlp<<<512, 256, 0, stream>>>(x, cb, lnw, lnb, W1, b1, W2, b2, ls, out);
}

// Round 8
// 139.085 us; speedup vs baseline: 4.7404x; 1.3015x over previous
//
#include <hip/hip_runtime.h>
#include <math.h>

#define NN 10000
#define GG 12
#define CC 64
#define AA 3
#define EE 50000
#define LN_EPS 1e-5f
#define MAXDEG 64   // max in-degree cap; Poisson(E/N=5) max ~17, 64 is far beyond

typedef __attribute__((ext_vector_type(4))) float f4;
typedef __attribute__((ext_vector_type(4))) short s4;

union S4U { s4 s; unsigned int w[2]; };

__device__ __forceinline__ float bl(float v, int i) {
    return __uint_as_float(__builtin_amdgcn_readlane(__float_as_uint(v), i));
}

// pack 4 f32 -> 4 bf16 (truncation) in frag element order k0..k3
__device__ __forceinline__ s4 pack4(float k0, float k1, float k2, float k3) {
    S4U t;
    t.w[0] = __builtin_amdgcn_perm(__float_as_uint(k1), __float_as_uint(k0), 0x07060302u);
    t.w[1] = __builtin_amdgcn_perm(__float_as_uint(k3), __float_as_uint(k2), 0x07060302u);
    return t.s;
}

__device__ __forceinline__ f4 mfma_bf16(s4 a, s4 b, f4 c) {
#if __has_builtin(__builtin_amdgcn_mfma_f32_16x16x16bf16_1k)
    return __builtin_amdgcn_mfma_f32_16x16x16bf16_1k(a, b, c, 0, 0, 0);
#else
    asm volatile("v_mfma_f32_16x16x16_bf16 %0, %1, %2, %0" : "+v"(c) : "v"(a), "v"(b));
    return c;
#endif
}

// ---------------- kernel 1: zero per-node counters ----------------
__global__ __launch_bounds__(256) void zero_cnt(int* __restrict__ cnt) {
    int i = blockIdx.x * 256 + threadIdx.x;
    if (i < NN) cnt[i] = 0;
}

// ---------------- kernel 2: bucket edges by destination; pack e | src<<17 ----------------
__global__ __launch_bounds__(256) void bucket_fill(const int* __restrict__ ei,
                                                   int* __restrict__ cnt,
                                                   int* __restrict__ elist) {
    int e = blockIdx.x * 256 + threadIdx.x;
    if (e < EE) {
        int src = ei[e];
        int dst = ei[EE + e];
        int pos = atomicAdd(&cnt[dst], 1);
        if (pos < MAXDEG) elist[dst * MAXDEG + pos] = e | (src << 17);
    }
}

// ---------------- kernel 3: conv gather via MFMA ----------------
// wave = node (4 waves/block). Per edge, 3 chains (a=0..2):
//   T_a[g,c] += attr[e,g,h,a] * x[src,h,c]   (M=12pad16, K=12pad16, N=64)
// = 12x v_mfma_f32_16x16x16_bf16, accumulated over ALL edges of the node.
// Epilogue: agg[g,c] = sum_a Wk[a,c] * T_a[g,c]  (lane-local in C layout).
// A-frag: lane holds A[m=l%16, k=(l/16)*4+j]; B-frag: B[k=(l/16)*4+j, n=l%16+16t].
// Lane-masked offsets keep every access inside the edge's 1728B attr block /
// the source node's 3072B x row; k=12..15 is zeroed via the B mask.
__global__ __launch_bounds__(256) void conv_mfma(
    const float* __restrict__ x, const float* __restrict__ attr,
    const float* __restrict__ Wk,
    const int* __restrict__ cnt, const int* __restrict__ elist,
    float* __restrict__ agg) {
    const int l  = threadIdx.x & 63;
    const int wv = threadIdx.x >> 6;
    const int n  = blockIdx.x * 4 + wv;
    const int lm = l & 15;
    const int lg = l >> 4;

    // per-lane constant byte offsets (loop-invariant)
    int aoff[3];
#pragma unroll
    for (int a = 0; a < 3; ++a)
        aoff[a] = (lm < 12 && lg < 3) ? (lm * 144 + lg * 48 + a * 4) : 0;
    const int boff = (lg < 3) ? (lg * 1024 + lm * 4) : 0;
    const unsigned bmsk = (lg < 3) ? 0xFFFFFFFFu : 0u;

    const int deg = min(cnt[n], MAXDEG);
    const int myE = elist[n * MAXDEG + l];      // whole edge list in one VGPR

    f4 acc[3][4];
#pragma unroll
    for (int a = 0; a < 3; ++a)
#pragma unroll
        for (int t = 0; t < 4; ++t) acc[a][t] = (f4){0.f, 0.f, 0.f, 0.f};

    for (int i = 0; i < deg; ++i) {
        const int p   = __builtin_amdgcn_readlane(myE, i);   // uniform
        const int e   = p & 0x1FFFF;
        const int src = p >> 17;
        const char* ab = (const char*)(attr + (size_t)e * (GG * GG * AA));
        const char* xb = (const char*)(x + src * (GG * CC));

        // raw loads (independent, issued together)
        float ar[3][4];
#pragma unroll
        for (int a = 0; a < 3; ++a) {
            const char* pa = ab + aoff[a];
#pragma unroll
            for (int j = 0; j < 4; ++j)
                ar[a][j] = *(const float*)(pa + j * 12);     // k=h step = 3 floats
        }
        float br[4][4];
#pragma unroll
        for (int t = 0; t < 4; ++t) {
            const char* pb = xb + boff + t * 64;
#pragma unroll
            for (int j = 0; j < 4; ++j)
                br[t][j] = *(const float*)(pb + j * 256);    // h step = 64 floats
        }

        s4 af[3], bf[4];
#pragma unroll
        for (int a = 0; a < 3; ++a)
            af[a] = pack4(ar[a][0], ar[a][1], ar[a][2], ar[a][3]);
#pragma unroll
        for (int t = 0; t < 4; ++t) {
            S4U u; u.s = pack4(br[t][0], br[t][1], br[t][2], br[t][3]);
            u.w[0] &= bmsk; u.w[1] &= bmsk;                  // zero k=12..15
            bf[t] = u.s;
        }

#pragma unroll
        for (int a = 0; a < 3; ++a)
#pragma unroll
            for (int t = 0; t < 4; ++t)
                acc[a][t] = mfma_bf16(af[a], bf[t], acc[a][t]);
    }

    // ---- epilogue: Wk combine (lane-local) + store ----
    float wk[3][4];
#pragma unroll
    for (int a = 0; a < 3; ++a)
#pragma unroll
        for (int t = 0; t < 4; ++t)
            wk[a][t] = Wk[a * CC + lm + 16 * t];

    float* ob = agg + n * (GG * CC);
    if (lg < 3) {                                  // g = lg*4 + r in 0..11
#pragma unroll
        for (int t = 0; t < 4; ++t) {
#pragma unroll
            for (int r = 0; r < 4; ++r) {
                const float m = fmaf(acc[0][t][r], wk[0][t],
                                fmaf(acc[1][t][r], wk[1][t],
                                     acc[2][t][r] * wk[2][t]));
                ob[(lg * 4 + r) * CC + lm + 16 * t] = m;
            }
        }
    }
}

// ---------------- kernel 4: LN + MLP(GELU) + layer_scale + residual ----------------
__global__ __launch_bounds__(256, 2) void ln_mlp(
    const float* __restrict__ x, const float* __restrict__ cb,
    const float* __restrict__ lnw, const float* __restrict__ lnb,
    const float* __restrict__ W1, const float* __restrict__ b1,
    const float* __restrict__ W2, const float* __restrict__ b2,
    const float* __restrict__ ls, float* __restrict__ out) {
    const int lane = threadIdx.x & 63;
    const int wv   = threadIdx.x >> 6;

    float w1r[CC], w2r[CC];
#pragma unroll
    for (int i = 0; i < CC; ++i) {
        w1r[i] = W1[i * CC + lane];
        w2r[i] = W2[i * CC + lane];
    }
    const float cbv = cb[lane];
    const float lw  = lnw[lane], lb = lnb[lane];
    const float bb1 = b1[lane],  bb2 = b2[lane];
    const float lsc = ls[lane];

    const int nf = NN * GG;
    const int nw = gridDim.x * 4;
    for (int f = blockIdx.x * 4 + wv; f < nf; f += nw) {
        const float v = out[f * CC + lane] + cbv;   // agg written here by conv_mfma
        float s = v, s2 = v * v;
#pragma unroll
        for (int off = 32; off; off >>= 1) {
            s  += __shfl_xor(s,  off);
            s2 += __shfl_xor(s2, off);
        }
        const float mu  = s * (1.f / 64.f);
        const float var = s2 * (1.f / 64.f) - mu * mu;
        const float hh  = (v - mu) * rsqrtf(var + LN_EPS) * lw + lb;

        float a0 = 0.f, a1 = 0.f, a2 = 0.f, a3 = 0.f;
#pragma unroll
        for (int i = 0; i < CC; i += 4) {
            a0 = fmaf(bl(hh, i),     w1r[i],     a0);
            a1 = fmaf(bl(hh, i + 1), w1r[i + 1], a1);
            a2 = fmaf(bl(hh, i + 2), w1r[i + 2], a2);
            a3 = fmaf(bl(hh, i + 3), w1r[i + 3], a3);
        }
        const float z  = ((a0 + a1) + (a2 + a3)) + bb1;
        const float gl = 0.5f * z * (1.f + erff(z * 0.70710678118654752f));

        float c0 = 0.f, c1 = 0.f, c2 = 0.f, c3 = 0.f;
#pragma unroll
        for (int i = 0; i < CC; i += 4) {
            c0 = fmaf(bl(gl, i),     w2r[i],     c0);
            c1 = fmaf(bl(gl, i + 1), w2r[i + 1], c1);
            c2 = fmaf(bl(gl, i + 2), w2r[i + 2], c2);
            c3 = fmaf(bl(gl, i + 3), w2r[i + 3], c3);
        }
        const float z2 = ((c0 + c1) + (c2 + c3)) + bb2;

        out[f * CC + lane] = fmaf(lsc, z2, x[f * CC + lane]);
    }
}

extern "C" void kernel_launch(void* const* d_in, const int* in_sizes, int n_in,
                              void* d_out, int out_size, void* d_ws, size_t ws_size,
                              hipStream_t stream) {
    const float* x    = (const float*)d_in[0];
    const float* attr = (const float*)d_in[1];
    const float* Wk   = (const float*)d_in[2];
    const float* cb   = (const float*)d_in[3];
    const float* lnw  = (const float*)d_in[4];
    const float* lnb  = (const float*)d_in[5];
    const float* W1   = (const float*)d_in[6];
    const float* b1   = (const float*)d_in[7];
    const float* W2   = (const float*)d_in[8];
    const float* b2   = (const float*)d_in[9];
    const float* ls   = (const float*)d_in[10];
    const int*   ei   = (const int*)d_in[11];
    float* out = (float*)d_out;

    int* cnt   = (int*)d_ws;            // NN ints
    int* elist = cnt + NN;              // NN*MAXDEG ints (2.56 MB)

    zero_cnt<<<(NN + 255) / 256, 256, 0, stream>>>(cnt);
    bucket_fill<<<(EE + 255) / 256, 256, 0, stream>>>(ei, cnt, elist);
    conv_mfma<<<NN / 4, 256, 0, stream>>>(x, attr, Wk, cnt, elist, out);
    ln_mlp<<<512, 256, 0, stream>>>(x, cb, lnw, lnb, W1, b1, W2, b2, ls, out);
}

// Round 9
// 81.675 us; speedup vs baseline: 8.0725x; 1.7029x over previous
//
#include <hip/hip_runtime.h>
#include <math.h>

#define NN 10000
#define GG 12
#define CC 64
#define AA 3
#define EE 50000
#define LN_EPS 1e-5f
#define MAXDEG 64   // max in-degree cap; Poisson(E/N=5) max ~17, 64 is far beyond

typedef __attribute__((ext_vector_type(4))) float f4;
typedef __attribute__((ext_vector_type(4))) short s4;

union S4U { s4 s; unsigned int w[2]; };

// pack 4 f32 -> 4 bf16 (truncation) in frag element order k0..k3
__device__ __forceinline__ s4 pack4(float k0, float k1, float k2, float k3) {
    S4U t;
    t.w[0] = __builtin_amdgcn_perm(__float_as_uint(k1), __float_as_uint(k0), 0x07060302u);
    t.w[1] = __builtin_amdgcn_perm(__float_as_uint(k3), __float_as_uint(k2), 0x07060302u);
    return t.s;
}

__device__ __forceinline__ f4 mfma_bf16(s4 a, s4 b, f4 c) {
#if __has_builtin(__builtin_amdgcn_mfma_f32_16x16x16bf16_1k)
    return __builtin_amdgcn_mfma_f32_16x16x16bf16_1k(a, b, c, 0, 0, 0);
#else
    asm volatile("v_mfma_f32_16x16x16_bf16 %0, %1, %2, %0" : "+v"(c) : "v"(a), "v"(b));
    return c;
#endif
}

// ---------------- kernel 1: zero per-node counters ----------------
__global__ __launch_bounds__(256) void zero_cnt(int* __restrict__ cnt) {
    int i = blockIdx.x * 256 + threadIdx.x;
    if (i < NN) cnt[i] = 0;
}

// ---------------- kernel 2: bucket edges by destination; pack e | src<<17 ----------------
__global__ __launch_bounds__(256) void bucket_fill(const int* __restrict__ ei,
                                                   int* __restrict__ cnt,
                                                   int* __restrict__ elist) {
    int e = blockIdx.x * 256 + threadIdx.x;
    if (e < EE) {
        int src = ei[e];
        int dst = ei[EE + e];
        int pos = atomicAdd(&cnt[dst], 1);
        if (pos < MAXDEG) elist[dst * MAXDEG + pos] = e | (src << 17);
    }
}

// ---------------- kernel 3: conv gather via MFMA (unchanged from round 8) ----------------
__global__ __launch_bounds__(256) void conv_mfma(
    const float* __restrict__ x, const float* __restrict__ attr,
    const float* __restrict__ Wk,
    const int* __restrict__ cnt, const int* __restrict__ elist,
    float* __restrict__ agg) {
    const int l  = threadIdx.x & 63;
    const int wv = threadIdx.x >> 6;
    const int n  = blockIdx.x * 4 + wv;
    const int lm = l & 15;
    const int lg = l >> 4;

    int aoff[3];
#pragma unroll
    for (int a = 0; a < 3; ++a)
        aoff[a] = (lm < 12 && lg < 3) ? (lm * 144 + lg * 48 + a * 4) : 0;
    const int boff = (lg < 3) ? (lg * 1024 + lm * 4) : 0;
    const unsigned bmsk = (lg < 3) ? 0xFFFFFFFFu : 0u;

    const int deg = min(cnt[n], MAXDEG);
    const int myE = elist[n * MAXDEG + l];

    f4 acc[3][4];
#pragma unroll
    for (int a = 0; a < 3; ++a)
#pragma unroll
        for (int t = 0; t < 4; ++t) acc[a][t] = (f4){0.f, 0.f, 0.f, 0.f};

    for (int i = 0; i < deg; ++i) {
        const int p   = __builtin_amdgcn_readlane(myE, i);
        const int e   = p & 0x1FFFF;
        const int src = p >> 17;
        const char* ab = (const char*)(attr + (size_t)e * (GG * GG * AA));
        const char* xb = (const char*)(x + src * (GG * CC));

        float ar[3][4];
#pragma unroll
        for (int a = 0; a < 3; ++a) {
            const char* pa = ab + aoff[a];
#pragma unroll
            for (int j = 0; j < 4; ++j)
                ar[a][j] = *(const float*)(pa + j * 12);
        }
        float br[4][4];
#pragma unroll
        for (int t = 0; t < 4; ++t) {
            const char* pb = xb + boff + t * 64;
#pragma unroll
            for (int j = 0; j < 4; ++j)
                br[t][j] = *(const float*)(pb + j * 256);
        }

        s4 af[3], bf[4];
#pragma unroll
        for (int a = 0; a < 3; ++a)
            af[a] = pack4(ar[a][0], ar[a][1], ar[a][2], ar[a][3]);
#pragma unroll
        for (int t = 0; t < 4; ++t) {
            S4U u; u.s = pack4(br[t][0], br[t][1], br[t][2], br[t][3]);
            u.w[0] &= bmsk; u.w[1] &= bmsk;
            bf[t] = u.s;
        }

#pragma unroll
        for (int a = 0; a < 3; ++a)
#pragma unroll
            for (int t = 0; t < 4; ++t)
                acc[a][t] = mfma_bf16(af[a], bf[t], acc[a][t]);
    }

    float wk[3][4];
#pragma unroll
    for (int a = 0; a < 3; ++a)
#pragma unroll
        for (int t = 0; t < 4; ++t)
            wk[a][t] = Wk[a * CC + lm + 16 * t];

    float* ob = agg + n * (GG * CC);
    if (lg < 3) {
#pragma unroll
        for (int t = 0; t < 4; ++t) {
#pragma unroll
            for (int r = 0; r < 4; ++r) {
                const float m = fmaf(acc[0][t][r], wk[0][t],
                                fmaf(acc[1][t][r], wk[1][t],
                                     acc[2][t][r] * wk[2][t]));
                ob[(lg * 4 + r) * CC + lm + 16 * t] = m;
            }
        }
    }
}

// ---------------- kernel 4: LN + MLP via MFMA ----------------
// wave = 16 fibers. Both GEMMs computed swapped (Z^T = W1^T @ H^T):
//  B-frag of GEMM1 = coalesced float4 loads of H (lane: fiber l%16, ch 4lg+j+16kt);
//  C-layout of GEMM1 == B-frag layout of GEMM2 (identity relayout; GELU elementwise);
//  epilogue transposed through per-wave XOR-swizzled LDS slot -> float4 x/out.
__global__ __launch_bounds__(256) void ln_mlp_mfma(
    const float* __restrict__ x, const float* __restrict__ cb,
    const float* __restrict__ lnw, const float* __restrict__ lnb,
    const float* __restrict__ W1, const float* __restrict__ b1,
    const float* __restrict__ W2, const float* __restrict__ b2,
    const float* __restrict__ ls, float* __restrict__ out) {
    __shared__ float sbuf[4][16 * 68];

    const int l  = threadIdx.x & 63;
    const int wv = threadIdx.x >> 6;
    const int lm = l & 15;
    const int lg = l >> 4;
    const int f0 = (blockIdx.x * 4 + wv) * 16;

    // ---- H tile: fiber l%16, channels 4lg+16kt .. +3 (agg lives in `out`) ----
    const float* aggp = out + (size_t)(f0 + lm) * CC + 4 * lg;
    f4 h4[4];
#pragma unroll
    for (int kt = 0; kt < 4; ++kt) h4[kt] = *(const f4*)(aggp + 16 * kt);

    f4 cb4[4], lw4[4], lb4[4];
#pragma unroll
    for (int kt = 0; kt < 4; ++kt) {
        cb4[kt] = *(const f4*)(cb  + 4 * lg + 16 * kt);
        lw4[kt] = *(const f4*)(lnw + 4 * lg + 16 * kt);
        lb4[kt] = *(const f4*)(lnb + 4 * lg + 16 * kt);
    }

    // ---- LayerNorm: in-lane partial sums + 2 shfl_xor across lane groups ----
    float s = 0.f, s2 = 0.f;
#pragma unroll
    for (int kt = 0; kt < 4; ++kt)
#pragma unroll
        for (int j = 0; j < 4; ++j) {
            const float v = h4[kt][j] + cb4[kt][j];
            h4[kt][j] = v;
            s += v; s2 += v * v;
        }
    s  += __shfl_xor(s, 16);  s  += __shfl_xor(s, 32);
    s2 += __shfl_xor(s2, 16); s2 += __shfl_xor(s2, 32);
    const float mu  = s * (1.f / 64.f);
    const float inv = rsqrtf(s2 * (1.f / 64.f) - mu * mu + LN_EPS);

    s4 hf[4];
#pragma unroll
    for (int kt = 0; kt < 4; ++kt) {
        const float n0 = (h4[kt][0] - mu) * inv * lw4[kt][0] + lb4[kt][0];
        const float n1 = (h4[kt][1] - mu) * inv * lw4[kt][1] + lb4[kt][1];
        const float n2 = (h4[kt][2] - mu) * inv * lw4[kt][2] + lb4[kt][2];
        const float n3 = (h4[kt][3] - mu) * inv * lw4[kt][3] + lb4[kt][3];
        hf[kt] = pack4(n0, n1, n2, n3);
    }

    // ---- W1^T fragments: A[m=lm+16mt, k=4lg+j+16kt] = W1[k*64+m] ----
    s4 w1f[4][4];
#pragma unroll
    for (int mt = 0; mt < 4; ++mt)
#pragma unroll
        for (int kt = 0; kt < 4; ++kt) {
            const int kb = 4 * lg + 16 * kt;
            const int m  = lm + 16 * mt;
            w1f[mt][kt] = pack4(W1[(kb + 0) * CC + m], W1[(kb + 1) * CC + m],
                                W1[(kb + 2) * CC + m], W1[(kb + 3) * CC + m]);
        }

    f4 z[4];
#pragma unroll
    for (int mt = 0; mt < 4; ++mt) z[mt] = (f4){0.f, 0.f, 0.f, 0.f};
#pragma unroll
    for (int mt = 0; mt < 4; ++mt)
#pragma unroll
        for (int kt = 0; kt < 4; ++kt)
            z[mt] = mfma_bf16(w1f[mt][kt], hf[kt], z[mt]);

    // ---- + b1, exact GELU; C-layout == next B-frag layout (identity) ----
    s4 gf[4];
#pragma unroll
    for (int mt = 0; mt < 4; ++mt) {
        const f4 b14 = *(const f4*)(b1 + 16 * mt + 4 * lg);
        float g[4];
#pragma unroll
        for (int r = 0; r < 4; ++r) {
            const float zz = z[mt][r] + b14[r];
            g[r] = 0.5f * zz * (1.f + erff(zz * 0.70710678118654752f));
        }
        gf[mt] = pack4(g[0], g[1], g[2], g[3]);
    }

    // ---- W2^T fragments + GEMM2 ----
    s4 w2f[4][4];
#pragma unroll
    for (int mt = 0; mt < 4; ++mt)
#pragma unroll
        for (int kt = 0; kt < 4; ++kt) {
            const int kb = 4 * lg + 16 * kt;
            const int m  = lm + 16 * mt;
            w2f[mt][kt] = pack4(W2[(kb + 0) * CC + m], W2[(kb + 1) * CC + m],
                                W2[(kb + 2) * CC + m], W2[(kb + 3) * CC + m]);
        }

    f4 o[4];
#pragma unroll
    for (int mt = 0; mt < 4; ++mt) o[mt] = (f4){0.f, 0.f, 0.f, 0.f};
#pragma unroll
    for (int mt = 0; mt < 4; ++mt)
#pragma unroll
        for (int kt = 0; kt < 4; ++kt)
            o[mt] = mfma_bf16(w2f[mt][kt], gf[kt], o[mt]);

    // ---- transpose through XOR-swizzled LDS slot: O^T[c2, f] -> [f][c2] ----
    float* sb = sbuf[wv];
    const int fbase = lm * 68;
    const int swz   = (l & 7) << 2;          // (f&7)<<2, f = lm
#pragma unroll
    for (int mt = 0; mt < 4; ++mt)
#pragma unroll
        for (int r = 0; r < 4; ++r)
            sb[fbase + ((16 * mt + 4 * lg + r) ^ swz)] = o[mt][r];

    const f4 b2q = *(const f4*)(b2 + 4 * lm);
    const f4 lsq = *(const f4*)(ls + 4 * lm);

#pragma unroll
    for (int rr = 0; rr < 4; ++rr) {
        const int R   = rr * 4 + lg;         // local fiber row
        const int col = 4 * lm;
        const f4 ov = *(const f4*)(&sb[R * 68 + (col ^ ((R & 7) << 2))]);
        const f4 xv = *(const f4*)(x + (size_t)(f0 + R) * CC + col);
        f4 res;
#pragma unroll
        for (int k = 0; k < 4; ++k)
            res[k] = fmaf(lsq[k], ov[k] + b2q[k], xv[k]);
        *(f4*)(out + (size_t)(f0 + R) * CC + col) = res;
    }
}

extern "C" void kernel_launch(void* const* d_in, const int* in_sizes, int n_in,
                              void* d_out, int out_size, void* d_ws, size_t ws_size,
                              hipStream_t stream) {
    const float* x    = (const float*)d_in[0];
    const float* attr = (const float*)d_in[1];
    const float* Wk   = (const float*)d_in[2];
    const float* cb   = (const float*)d_in[3];
    const float* lnw  = (const float*)d_in[4];
    const float* lnb  = (const float*)d_in[5];
    const float* W1   = (const float*)d_in[6];
    const float* b1   = (const float*)d_in[7];
    const float* W2   = (const float*)d_in[8];
    const float* b2   = (const float*)d_in[9];
    const float* ls   = (const float*)d_in[10];
    const int*   ei   = (const int*)d_in[11];
    float* out = (float*)d_out;

    int* cnt   = (int*)d_ws;            // NN ints
    int* elist = cnt + NN;              // NN*MAXDEG ints (2.56 MB)

    zero_cnt<<<(NN + 255) / 256, 256, 0, stream>>>(cnt);
    bucket_fill<<<(EE + 255) / 256, 256, 0, stream>>>(ei, cnt, elist);
    conv_mfma<<<NN / 4, 256, 0, stream>>>(x, attr, Wk, cnt, elist, out);
    // 120000 fibers / (4 waves * 16 fibers) = 1875 blocks
    ln_mlp_mfma<<<1875, 256, 0, stream>>>(x, cb, lnw, lnb, W1, b1, W2, b2, ls, out);
}

// Round 10
// 77.447 us; speedup vs baseline: 8.5132x; 1.0546x over previous
//
#include <hip/hip_runtime.h>
#include <math.h>

#define NN 10000
#define GG 12
#define CC 64
#define AA 3
#define EE 50000
#define LN_EPS 1e-5f
#define MAXDEG 64   // max in-degree cap; Poisson(E/N=5) max ~17, 64 is far beyond

typedef __attribute__((ext_vector_type(4))) float f4;
typedef __attribute__((ext_vector_type(4))) short s4;

union S4U { s4 s; unsigned int w[2]; };

// pack 4 f32 -> 4 bf16 (truncation) in frag element order k0..k3
__device__ __forceinline__ s4 pack4(float k0, float k1, float k2, float k3) {
    S4U t;
    t.w[0] = __builtin_amdgcn_perm(__float_as_uint(k1), __float_as_uint(k0), 0x07060302u);
    t.w[1] = __builtin_amdgcn_perm(__float_as_uint(k3), __float_as_uint(k2), 0x07060302u);
    return t.s;
}

__device__ __forceinline__ f4 mfma_bf16(s4 a, s4 b, f4 c) {
#if __has_builtin(__builtin_amdgcn_mfma_f32_16x16x16bf16_1k)
    return __builtin_amdgcn_mfma_f32_16x16x16bf16_1k(a, b, c, 0, 0, 0);
#else
    asm volatile("v_mfma_f32_16x16x16_bf16 %0, %1, %2, %0" : "+v"(c) : "v"(a), "v"(b));
    return c;
#endif
}

// ---------------- kernel 1: zero per-node counters ----------------
__global__ __launch_bounds__(256) void zero_cnt(int* __restrict__ cnt) {
    int i = blockIdx.x * 256 + threadIdx.x;
    if (i < NN) cnt[i] = 0;
}

// ---------------- kernel 2: bucket edges by destination; pack e | src<<17 ----------------
__global__ __launch_bounds__(256) void bucket_fill(const int* __restrict__ ei,
                                                   int* __restrict__ cnt,
                                                   int* __restrict__ elist) {
    int e = blockIdx.x * 256 + threadIdx.x;
    if (e < EE) {
        int src = ei[e];
        int dst = ei[EE + e];
        int pos = atomicAdd(&cnt[dst], 1);
        if (pos < MAXDEG) elist[dst * MAXDEG + pos] = e | (src << 17);
    }
}

// ---------------- kernel 3: conv gather via MFMA + LDS-staged attr ----------------
// wave = node (4 waves/block). Per edge:
//   - attr block (432 f, contiguous) loaded COALESCED: 2x dwordx4/lane (27 lines
//     instead of 324 line-touches of the scattered r8 gather),
//   - staged in a PRIVATE double-buffered LDS slot (no barriers, same-wave lgkm),
//   - lane's 12 fragment scalars read back as 3x ds_read_b128 at lm*36+lg*12
//     (16B-aligned by construction: 36lm+12lg = 4*(9lm+3lg)),
//   - depth-1 software pipeline: bf packed early so xr reloads in place; attr
//     regs are consumed by ds_write at issue, then reloaded for edge i+1.
__global__ __launch_bounds__(256) void conv_mfma(
    const float* __restrict__ x, const float* __restrict__ attr,
    const float* __restrict__ Wk,
    const int* __restrict__ cnt, const int* __restrict__ elist,
    float* __restrict__ agg) {
    __shared__ float lsa[4][2][432];            // 13.8 KB: 4 waves x 2 slots

    const int l  = threadIdx.x & 63;
    const int wv = threadIdx.x >> 6;
    const int n  = blockIdx.x * 4 + wv;
    const int lm = l & 15;
    const int lg = l >> 4;

    // x (B-operand) lane offset, as verified in r8
    const int boff = (lg < 3) ? (lg * 1024 + lm * 4) : 0;     // bytes
    const unsigned bmsk = (lg < 3) ? 0xFFFFFFFFu : 0u;
    // attr fragment base in the slot (dwords); inactive lanes read dwords 0..11
    const int fbase = (lm < 12 && lg < 3) ? (lm * 36 + lg * 12) : 0;
    // coalesced attr staging offsets
    const int a1l   = (l < 44) ? l : 43;                      // clamp for loads

    const int deg = min(cnt[n], MAXDEG);
    const int myE = elist[n * MAXDEG + l];      // whole edge list in one VGPR

    f4 acc[3][4];
#pragma unroll
    for (int a = 0; a < 3; ++a)
#pragma unroll
        for (int t = 0; t < 4; ++t) acc[a][t] = (f4){0.f, 0.f, 0.f, 0.f};

    f4 A0, A1;
    float xr[16];

    // ---- prologue: load edge 0 into regs ----
    if (deg > 0) {
        const int p   = __builtin_amdgcn_readlane(myE, 0);
        const char* ab = (const char*)(attr + (size_t)(p & 0x1FFFF) * (GG * GG * AA));
        const char* xb = (const char*)(x + (p >> 17) * (GG * CC));
        A0 = *(const f4*)(ab + 16 * l);
        A1 = *(const f4*)(ab + 1024 + 16 * a1l);
#pragma unroll
        for (int t = 0; t < 4; ++t)
#pragma unroll
            for (int j = 0; j < 4; ++j)
                xr[4 * t + j] = *(const float*)(xb + boff + t * 64 + j * 256);
    }

    for (int i = 0; i < deg; ++i) {
        float* sw = &lsa[wv][i & 1][0];

        // (1) stage edge i's attr block to LDS (regs consumed at issue)
        *(f4*)(sw + 4 * l) = A0;
        if (l < 44) *(f4*)(sw + 256 + 4 * l) = A1;

        // (2) pack bf from xr NOW (frees xr for the prefetch)
        s4 bf[4];
#pragma unroll
        for (int t = 0; t < 4; ++t) {
            S4U u; u.s = pack4(xr[4 * t], xr[4 * t + 1], xr[4 * t + 2], xr[4 * t + 3]);
            u.w[0] &= bmsk; u.w[1] &= bmsk;
            bf[t] = u.s;
        }

        // (3) prefetch edge i+1 (attr + x) into the same regs
        if (i + 1 < deg) {
            const int p   = __builtin_amdgcn_readlane(myE, i + 1);
            const char* ab = (const char*)(attr + (size_t)(p & 0x1FFFF) * (GG * GG * AA));
            const char* xb = (const char*)(x + (p >> 17) * (GG * CC));
            A0 = *(const f4*)(ab + 16 * l);
            A1 = *(const f4*)(ab + 1024 + 16 * a1l);
#pragma unroll
            for (int t = 0; t < 4; ++t)
#pragma unroll
                for (int j = 0; j < 4; ++j)
                    xr[4 * t + j] = *(const float*)(xb + boff + t * 64 + j * 256);
        }

        // (4) read edge i's A-fragments: 12 contiguous dwords = 3x ds_read_b128
        const float* sr = sw + fbase;
        const f4 q0 = *(const f4*)(sr);
        const f4 q1 = *(const f4*)(sr + 4);
        const f4 q2 = *(const f4*)(sr + 8);

        // (5) af[a], element j = dword (3j+a):
        //   a=0: 0,3,6,9   a=1: 1,4,7,10   a=2: 2,5,8,11
        s4 af[3];
        af[0] = pack4(q0[0], q0[3], q1[2], q2[1]);
        af[1] = pack4(q0[1], q1[0], q1[3], q2[2]);
        af[2] = pack4(q0[2], q1[1], q2[0], q2[3]);

        // (6) 12 MFMA
#pragma unroll
        for (int a = 0; a < 3; ++a)
#pragma unroll
            for (int t = 0; t < 4; ++t)
                acc[a][t] = mfma_bf16(af[a], bf[t], acc[a][t]);
    }

    // ---- epilogue: Wk combine (lane-local, verified r8) + store ----
    float wk[3][4];
#pragma unroll
    for (int a = 0; a < 3; ++a)
#pragma unroll
        for (int t = 0; t < 4; ++t)
            wk[a][t] = Wk[a * CC + lm + 16 * t];

    float* ob = agg + n * (GG * CC);
    if (lg < 3) {
#pragma unroll
        for (int t = 0; t < 4; ++t) {
#pragma unroll
            for (int r = 0; r < 4; ++r) {
                const float m = fmaf(acc[0][t][r], wk[0][t],
                                fmaf(acc[1][t][r], wk[1][t],
                                     acc[2][t][r] * wk[2][t]));
                ob[(lg * 4 + r) * CC + lm + 16 * t] = m;
            }
        }
    }
}

// ---------------- kernel 4: LN + MLP via MFMA (unchanged from round 9) ----------------
__global__ __launch_bounds__(256) void ln_mlp_mfma(
    const float* __restrict__ x, const float* __restrict__ cb,
    const float* __restrict__ lnw, const float* __restrict__ lnb,
    const float* __restrict__ W1, const float* __restrict__ b1,
    const float* __restrict__ W2, const float* __restrict__ b2,
    const float* __restrict__ ls, float* __restrict__ out) {
    __shared__ float sbuf[4][16 * 68];

    const int l  = threadIdx.x & 63;
    const int wv = threadIdx.x >> 6;
    const int lm = l & 15;
    const int lg = l >> 4;
    const int f0 = (blockIdx.x * 4 + wv) * 16;

    const float* aggp = out + (size_t)(f0 + lm) * CC + 4 * lg;
    f4 h4[4];
#pragma unroll
    for (int kt = 0; kt < 4; ++kt) h4[kt] = *(const f4*)(aggp + 16 * kt);

    f4 cb4[4], lw4[4], lb4[4];
#pragma unroll
    for (int kt = 0; kt < 4; ++kt) {
        cb4[kt] = *(const f4*)(cb  + 4 * lg + 16 * kt);
        lw4[kt] = *(const f4*)(lnw + 4 * lg + 16 * kt);
        lb4[kt] = *(const f4*)(lnb + 4 * lg + 16 * kt);
    }

    float s = 0.f, s2 = 0.f;
#pragma unroll
    for (int kt = 0; kt < 4; ++kt)
#pragma unroll
        for (int j = 0; j < 4; ++j) {
            const float v = h4[kt][j] + cb4[kt][j];
            h4[kt][j] = v;
            s += v; s2 += v * v;
        }
    s  += __shfl_xor(s, 16);  s  += __shfl_xor(s, 32);
    s2 += __shfl_xor(s2, 16); s2 += __shfl_xor(s2, 32);
    const float mu  = s * (1.f / 64.f);
    const float inv = rsqrtf(s2 * (1.f / 64.f) - mu * mu + LN_EPS);

    s4 hf[4];
#pragma unroll
    for (int kt = 0; kt < 4; ++kt) {
        const float n0 = (h4[kt][0] - mu) * inv * lw4[kt][0] + lb4[kt][0];
        const float n1 = (h4[kt][1] - mu) * inv * lw4[kt][1] + lb4[kt][1];
        const float n2 = (h4[kt][2] - mu) * inv * lw4[kt][2] + lb4[kt][2];
        const float n3 = (h4[kt][3] - mu) * inv * lw4[kt][3] + lb4[kt][3];
        hf[kt] = pack4(n0, n1, n2, n3);
    }

    s4 w1f[4][4];
#pragma unroll
    for (int mt = 0; mt < 4; ++mt)
#pragma unroll
        for (int kt = 0; kt < 4; ++kt) {
            const int kb = 4 * lg + 16 * kt;
            const int m  = lm + 16 * mt;
            w1f[mt][kt] = pack4(W1[(kb + 0) * CC + m], W1[(kb + 1) * CC + m],
                                W1[(kb + 2) * CC + m], W1[(kb + 3) * CC + m]);
        }

    f4 z[4];
#pragma unroll
    for (int mt = 0; mt < 4; ++mt) z[mt] = (f4){0.f, 0.f, 0.f, 0.f};
#pragma unroll
    for (int mt = 0; mt < 4; ++mt)
#pragma unroll
        for (int kt = 0; kt < 4; ++kt)
            z[mt] = mfma_bf16(w1f[mt][kt], hf[kt], z[mt]);

    s4 gf[4];
#pragma unroll
    for (int mt = 0; mt < 4; ++mt) {
        const f4 b14 = *(const f4*)(b1 + 16 * mt + 4 * lg);
        float g[4];
#pragma unroll
        for (int r = 0; r < 4; ++r) {
            const float zz = z[mt][r] + b14[r];
            g[r] = 0.5f * zz * (1.f + erff(zz * 0.70710678118654752f));
        }
        gf[mt] = pack4(g[0], g[1], g[2], g[3]);
    }

    s4 w2f[4][4];
#pragma unroll
    for (int mt = 0; mt < 4; ++mt)
#pragma unroll
        for (int kt = 0; kt < 4; ++kt) {
            const int kb = 4 * lg + 16 * kt;
            const int m  = lm + 16 * mt;
            w2f[mt][kt] = pack4(W2[(kb + 0) * CC + m], W2[(kb + 1) * CC + m],
                                W2[(kb + 2) * CC + m], W2[(kb + 3) * CC + m]);
        }

    f4 o[4];
#pragma unroll
    for (int mt = 0; mt < 4; ++mt) o[mt] = (f4){0.f, 0.f, 0.f, 0.f};
#pragma unroll
    for (int mt = 0; mt < 4; ++mt)
#pragma unroll
        for (int kt = 0; kt < 4; ++kt)
            o[mt] = mfma_bf16(w2f[mt][kt], gf[kt], o[mt]);

    float* sb = sbuf[wv];
    const int fbase = lm * 68;
    const int swz   = (l & 7) << 2;
#pragma unroll
    for (int mt = 0; mt < 4; ++mt)
#pragma unroll
        for (int r = 0; r < 4; ++r)
            sb[fbase + ((16 * mt + 4 * lg + r) ^ swz)] = o[mt][r];

    const f4 b2q = *(const f4*)(b2 + 4 * lm);
    const f4 lsq = *(const f4*)(ls + 4 * lm);

#pragma unroll
    for (int rr = 0; rr < 4; ++rr) {
        const int R   = rr * 4 + lg;
        const int col = 4 * lm;
        const f4 ov = *(const f4*)(&sb[R * 68 + (col ^ ((R & 7) << 2))]);
        const f4 xv = *(const f4*)(x + (size_t)(f0 + R) * CC + col);
        f4 res;
#pragma unroll
        for (int k = 0; k < 4; ++k)
            res[k] = fmaf(lsq[k], ov[k] + b2q[k], xv[k]);
        *(f4*)(out + (size_t)(f0 + R) * CC + col) = res;
    }
}

extern "C" void kernel_launch(void* const* d_in, const int* in_sizes, int n_in,
                              void* d_out, int out_size, void* d_ws, size_t ws_size,
                              hipStream_t stream) {
    const float* x    = (const float*)d_in[0];
    const float* attr = (const float*)d_in[1];
    const float* Wk   = (const float*)d_in[2];
    const float* cb   = (const float*)d_in[3];
    const float* lnw  = (const float*)d_in[4];
    const float* lnb  = (const float*)d_in[5];
    const float* W1   = (const float*)d_in[6];
    const float* b1   = (const float*)d_in[7];
    const float* W2   = (const float*)d_in[8];
    const float* b2   = (const float*)d_in[9];
    const float* ls   = (const float*)d_in[10];
    const int*   ei   = (const int*)d_in[11];
    float* out = (float*)d_out;

    int* cnt   = (int*)d_ws;            // NN ints
    int* elist = cnt + NN;              // NN*MAXDEG ints (2.56 MB)

    zero_cnt<<<(NN + 255) / 256, 256, 0, stream>>>(cnt);
    bucket_fill<<<(EE + 255) / 256, 256, 0, stream>>>(ei, cnt, elist);
    conv_mfma<<<NN / 4, 256, 0, stream>>>(x, attr, Wk, cnt, elist, out);
    ln_mlp_mfma<<<1875, 256, 0, stream>>>(x, cb, lnw, lnb, W1, b1, W2, b2, ls, out);
}